// Round 10
// baseline (7294.180 us; speedup 1.0000x reference)
//
#include <hip/hip_runtime.h>
#include <hip/hip_bf16.h>

typedef __attribute__((ext_vector_type(8))) short short8;
typedef __attribute__((ext_vector_type(4))) float f32x4;
typedef __attribute__((ext_vector_type(4))) int i32x4;
typedef unsigned short u16;
typedef unsigned int u32;
typedef unsigned long long u64;

#define MFMA_BF16(a, b, c) __builtin_amdgcn_mfma_f32_16x16x32_bf16((a), (b), (c), 0, 0, 0)

// ---------------- workspace layout (bytes) ----------------
static constexpr size_t OFF_W   = 0;                       // 4 x [4096][1024] bf16 = 32MB
static constexpr size_t OFF_B0  = 33554432;                // 4096 f32 (bi0+bh0)
static constexpr size_t OFF_B1  = OFF_B0 + 16384;          // 4096 f32 (bi1+bh1)
static constexpr size_t OFF_H0  = OFF_B1 + 16384;          // hinit: 256KB zeroed
static constexpr size_t OFF_H1F = OFF_H0 + 262144;         // [32][1024] f32 (final h1)
static constexpr size_t OFF_XE  = OFF_H1F + 131072;        // [16384][1024] bf16 = 32MB
static constexpr size_t OFF_X0  = OFF_XE + 33554432;       // packed gates Xp = 128MB (also slot arena)
static constexpr size_t WS_NEED = OFF_X0 + 134217728;      // ~192.5 MB
// dense barrier flags: flagsA[256] + flagsB[256] u32, on xe tail (dead after x0_gemm)
static constexpr size_t OFF_FLG = OFF_X0 - 4096;

// Packed gates: Xp[t][blk][b][j][g] u16 (8B chunk per activation thread), bypass-read.
// Slot scheme (write-once arena): slice(s) = Xp + s*131072 (u16). h0[i] bypass-stored
// at L0 iter i into slice(i-1)+0 (i=0 -> hinit+65536); h1[t] bypass-stored at L1 iter t
// into slice(t)+32768. Cached reads only AFTER the (unique) bypass write, gated by
// flags; gate reads are bypass -> every address L2-allocated at most once, never stale.
// flagA[blk]=i+1: h0[i] visible. flagB[blk]=t+1: h1[t] visible.
// Two decoupled pipelines per block: waves 0/1 = layer 0 (critical recurrence, only
// depends on flagsA); waves 2/3 = layer 1 (lags one step; depends on flagsA+flagsB).

// ---------------- helpers ----------------
__device__ __forceinline__ u16 f2bf(float f) {
  u32 x = __builtin_bit_cast(u32, f);
  x += 0x7fffu + ((x >> 16) & 1u);   // RNE (inputs are finite)
  return (u16)(x >> 16);
}
__device__ __forceinline__ float bf2f(u16 u) {
  return __builtin_bit_cast(float, (u32)u << 16);
}
__device__ __forceinline__ float sigm(float x) { return 1.f / (1.f + expf(-x)); }

__device__ __forceinline__ void sysstore64(void* p, u64 v) {
  __hip_atomic_store((u64*)p, v, __ATOMIC_RELAXED, __HIP_MEMORY_SCOPE_SYSTEM);
}
__device__ __forceinline__ u64 sysload64(const void* p) {
  return __hip_atomic_load((const u64*)p, __ATOMIC_RELAXED, __HIP_MEMORY_SCOPE_SYSTEM);
}

__device__ __forceinline__ void gload_lds16(const u16* gsrc, u16* ldst) {
  __builtin_amdgcn_global_load_lds(
      (__attribute__((address_space(1))) void*)(u16*)gsrc,
      (__attribute__((address_space(3))) void*)ldst, 16, 0, 0);
}

// wave-wide flag poll: 64 lanes x 4 flags (16B bypass load each) = 256 flags
__device__ __forceinline__ void poll256(const u32* fquad, u32 target) {
  while (true) {
    i32x4 v;
    asm volatile("global_load_dwordx4 %0, %1, off sc0 sc1"
                 : "=&v"(v) : "v"(fquad));
    asm volatile("s_waitcnt vmcnt(0)" ::: "memory");
    u32 m01 = min((u32)v.x, (u32)v.y);
    u32 m23 = min((u32)v.z, (u32)v.w);
    if (__all(min(m01, m23) >= target)) break;
  }
}
// dual poll: flagsA >= ta AND flagsB >= tb
__device__ __forceinline__ void pollAB(const u32* fa, u32 ta, const u32* fb, u32 tb) {
  while (true) {
    i32x4 va, vb;
    asm volatile("global_load_dwordx4 %0, %2, off sc0 sc1\n\t"
                 "global_load_dwordx4 %1, %3, off sc0 sc1"
                 : "=&v"(va), "=&v"(vb) : "v"(fa), "v"(fb));
    asm volatile("s_waitcnt vmcnt(0)" ::: "memory");
    u32 ma = min(min((u32)va.x, (u32)va.y), min((u32)va.z, (u32)va.w));
    u32 mb = min(min((u32)vb.x, (u32)vb.y), min((u32)vb.z, (u32)vb.w));
    if (__all((ma >= ta) && (mb >= tb))) break;
  }
}

// ---------------- prep: fp32 weights -> bf16 ----------------
__global__ void prep_w_kernel(const float* __restrict__ Wi0, const float* __restrict__ Wh0,
                              const float* __restrict__ Wi1, const float* __restrict__ Wh1,
                              u16* __restrict__ dst) {
  size_t e = ((size_t)blockIdx.x * 256 + threadIdx.x) * 4;   // 16M elements total
  int mat = (int)(e >> 22);
  size_t off = e & ((1ull << 22) - 1);
  const float* src = (mat == 0) ? Wi0 : (mat == 1) ? Wh0 : (mat == 2) ? Wi1 : Wh1;
  float4 v = *(const float4*)(src + off);
  ushort4 o;
  o.x = f2bf(v.x); o.y = f2bf(v.y); o.z = f2bf(v.z); o.w = f2bf(v.w);
  *(ushort4*)(dst + e) = o;
}

__global__ void prep_b_kernel(const float* __restrict__ bi0, const float* __restrict__ bh0,
                              const float* __restrict__ bi1, const float* __restrict__ bh1,
                              float* __restrict__ b0, float* __restrict__ b1) {
  int i = blockIdx.x * 256 + threadIdx.x;   // 4096
  b0[i] = bi0[i] + bh0[i];
  b1[i] = bi1[i] + bh1[i];
}

// ---------------- embedding gather ----------------
__global__ void embed_kernel(const int* __restrict__ x, const float* __restrict__ emb,
                             u16* __restrict__ xe) {
  int m = blockIdx.x;            // m = t*32 + b
  int b = m & 31, t = m >> 5;
  int id = x[b * 512 + t];
  float4 v = ((const float4*)(emb + (size_t)id * 1024))[threadIdx.x];
  ushort4 o;
  o.x = f2bf(v.x); o.y = f2bf(v.y); o.z = f2bf(v.z); o.w = f2bf(v.w);
  *(ushort4*)(xe + (size_t)m * 1024 + threadIdx.x * 4) = o;
}

// ---------------- X0 GEMM -> block-packed gate layout Xp (+bias) ----------------
__global__ void x0_gemm_kernel(const u16* __restrict__ A, const u16* __restrict__ W,
                               const float* __restrict__ bias, u16* __restrict__ Xp) {
  __shared__ u16 lds[2][2][8192];   // [buf][A/B][128 rows x 64 cols]
  const int tid = threadIdx.x, l = tid & 63, w = tid >> 6;
  const int n0 = blockIdx.x * 128, m0 = blockIdx.y * 128;
  const int wm = w >> 1, wn = w & 1;
  const int row8 = l >> 3, u = l & 7;

  f32x4 acc[4][4];
#pragma unroll
  for (int a1 = 0; a1 < 4; ++a1)
#pragma unroll
    for (int a2 = 0; a2 < 4; ++a2) acc[a1][a2] = (f32x4){0.f, 0.f, 0.f, 0.f};

  auto stage = [&](int buf, int kt) {
    const int k0 = kt * 64;
#pragma unroll
    for (int q = 0; q < 4; ++q) {
      const int ld = w * 4 + q;
      const int row = ld * 8 + row8;
      const int sw = (u ^ (row & 7)) * 8;
      gload_lds16(A + (size_t)(m0 + row) * 1024 + k0 + sw, &lds[buf][0][ld * 512]);
      gload_lds16(W + (size_t)(n0 + row) * 1024 + k0 + sw, &lds[buf][1][ld * 512]);
    }
  };

  stage(0, 0);
  __syncthreads();

  for (int kt = 0; kt < 16; ++kt) {
    const int buf = kt & 1;
    if (kt < 15) stage(buf ^ 1, kt + 1);
    const u16* la = lds[buf][0];
    const u16* lb = lds[buf][1];
#pragma unroll
    for (int kk = 0; kk < 2; ++kk) {
      const int c = kk * 4 + (l >> 4);
      const int csw = (c ^ (l & 7)) * 8;    // row&7 == l&7 for all frag rows
      short8 af[4], bf[4];
#pragma unroll
      for (int mi = 0; mi < 4; ++mi) {
        int row = wm * 64 + mi * 16 + (l & 15);
        af[mi] = *(const short8*)(la + row * 64 + csw);
      }
#pragma unroll
      for (int ni = 0; ni < 4; ++ni) {
        int row = wn * 64 + ni * 16 + (l & 15);
        bf[ni] = *(const short8*)(lb + row * 64 + csw);
      }
#pragma unroll
      for (int mi = 0; mi < 4; ++mi)
#pragma unroll
        for (int ni = 0; ni < 4; ++ni)
          acc[mi][ni] = MFMA_BF16(af[mi], bf[ni], acc[mi][ni]);
    }
    __syncthreads();
  }

  // epilogue: packed write Xp[t][blkid][b][j][g]
#pragma unroll
  for (int ni = 0; ni < 4; ++ni) {
    int col = n0 + wn * 64 + ni * 16 + (l & 15);
    int g = col >> 10, blkid = (col & 1023) >> 2, j = col & 3;
    float bv = bias[col];
#pragma unroll
    for (int mi = 0; mi < 4; ++mi) {
#pragma unroll
      for (int r = 0; r < 4; ++r) {
        int row = m0 + wm * 64 + mi * 16 + (l >> 4) * 4 + r;
        int t = row >> 5, b = row & 31;
        Xp[(size_t)t * 131072 + blkid * 512 + b * 16 + j * 4 + g] =
            f2bf(acc[mi][ni][r] + bv);
      }
    }
  }
}

// ---------------- persistent recurrent kernel: two decoupled pipelines ----------------
__launch_bounds__(256, 1)
__global__ void lstm_kernel(const u16* __restrict__ wbf, const float* __restrict__ b1v,
                            const u16* __restrict__ Xp, u16* __restrict__ hinit,
                            float* __restrict__ h1f, u32* __restrict__ flagsA) {
  extern __shared__ char smem[];
  u16* wlds = (u16*)smem;                          // 3 * 16384 u16 = 98304 B
  float* gates0 = (float*)(smem + 98304);          // [32][16] layer-0 Wh0.h0
  float* part1  = (float*)(smem + 98304 + 2048);   // [32][16] layer-1 Wi1.h0 + Wh1.h1
  volatile u32* tok = (volatile u32*)(smem + 104448); // [0]=tokA [8]=goA [16]=tokB [24]=goB

  const int tid = threadIdx.x;
  const int l = tid & 63, w = tid >> 6;
  const int blk = blockIdx.x;
  const int hbase = blk * 4;
  u32* flagsB = flagsA + 256;
  u16* Xw = (u16*)Xp;

  // ---- fill weight LDS in MFMA fragment order (Wh0 @0, Wi1 @16384, Wh1 @32768 u16)
  for (int m = 0; m < 3; ++m) {
    const u16* Wm = wbf + (size_t)(m + 1) * (4096 * 1024);
    for (int s = tid; s < 2048; s += 256) {
      int kk = s >> 6, ll = s & 63;
      int nl = ll & 15, hi = ll >> 4;
      int gr = (nl >> 2) * 1024 + hbase + (nl & 3);
      short8 v = *(const short8*)(Wm + (size_t)gr * 1024 + kk * 32 + hi * 8);
      *(short8*)(wlds + m * 16384 + kk * 512 + ll * 8) = v;
    }
  }
  if (tid == 0) { tok[0] = 0; tok[8] = 0; tok[16] = 0; tok[24] = 0; }
  __syncthreads();   // last block-wide sync; pipelines decouple below

  const u32* fqA = flagsA + l * 4;
  const u32* fqB = flagsB + l * 4;
  const int mt = w & 1;

  if (w < 2) {
    // ============ layer-0 pipeline (the critical recurrence) ============
    const int ab = tid >> 2, aj = tid & 3;       // tid 0..127
    float c0 = 0.f;
    u64 gcur = sysload64(Xp + blk * 512 + ab * 16 + aj * 4);
    for (int i = 0; i < 512; ++i) {
      const u16* rh0 = (i == 0) ? hinit : (i == 1) ? hinit + 65536
                                                   : Xp + (size_t)(i - 2) * 131072;
      u16* wh0 = (i == 0) ? hinit + 65536 : Xw + (size_t)(i - 1) * 131072;
      if (i) {
        if (w == 0) { poll256(fqA, (u32)i); if (l == 0) tok[8] = (u32)i; }
        else { while (tok[8] < (u32)i) __builtin_amdgcn_s_sleep(1); }
      }
      __builtin_amdgcn_sched_barrier(0);
      asm volatile("" ::: "memory");

      const u16* abase = rh0 + (mt * 16 + (l & 15)) * 1024 + ((l >> 4) * 8);
      short8 ar[32];
#pragma unroll
      for (int kk = 0; kk < 32; ++kk) ar[kk] = *(const short8*)(abase + kk * 32);
      u64 gnext = 0;
      if (i + 1 < 512)
        gnext = sysload64(Xp + (size_t)(i + 1) * 131072 + blk * 512 + ab * 16 + aj * 4);

      f32x4 a0 = {0,0,0,0}, a1 = {0,0,0,0};
#pragma unroll
      for (int kk = 0; kk < 16; ++kk) {
        a0 = MFMA_BF16(ar[2*kk],   *(const short8*)(wlds + (2*kk) * 512 + l * 8), a0);
        a1 = MFMA_BF16(ar[2*kk+1], *(const short8*)(wlds + (2*kk+1) * 512 + l * 8), a1);
      }
#pragma unroll
      for (int r = 0; r < 4; ++r)
        gates0[(mt * 16 + (l >> 4) * 4 + r) * 16 + (l & 15)] = a0[r] + a1[r];

      // act0 — same-wave LDS producer/consumer (rows 0-15 wave0, 16-31 wave1)
      float gi = gates0[ab * 16 + aj]      + bf2f((u16)gcur);
      float gf = gates0[ab * 16 + 4 + aj]  + bf2f((u16)(gcur >> 16));
      float gg = gates0[ab * 16 + 8 + aj]  + bf2f((u16)(gcur >> 32));
      float go = gates0[ab * 16 + 12 + aj] + bf2f((u16)(gcur >> 48));
      c0 = sigm(gf) * c0 + sigm(gi) * tanhf(gg);
      float h = sigm(go) * tanhf(c0);
      u32 hv = (u32)f2bf(h);
      u32 p1 = (u32)__shfl_xor((int)hv, 1);
      u32 lo = (aj & 1) ? ((p1 & 0xffff) | (hv << 16)) : ((hv & 0xffff) | (p1 << 16));
      u32 p2 = (u32)__shfl_xor((int)lo, 2);
      if (aj == 0)
        sysstore64(wh0 + ab * 1024 + hbase, (u64)lo | ((u64)p2 << 32));
      gcur = gnext;

      asm volatile("s_waitcnt vmcnt(0)" ::: "memory");   // own h0 stores ACKed at MALL
      if (w == 1) { if (l == 0) tok[0] = (u32)(i + 1); }
      else {
        while (tok[0] < (u32)(i + 1)) __builtin_amdgcn_s_sleep(1);
        if (l == 0)
          __hip_atomic_store(&flagsA[blk], (u32)(i + 1), __ATOMIC_RELAXED,
                             __HIP_MEMORY_SCOPE_SYSTEM);
      }
    }
  } else {
    // ============ layer-1 pipeline (lags one step; off critical path) ============
    const int at = tid & 127, ab = at >> 2, aj = at & 3;
    float c1 = 0.f;
    const float b1i  = b1v[hbase + aj];
    const float b1fv = b1v[1024 + hbase + aj];
    const float b1g  = b1v[2048 + hbase + aj];
    const float b1o  = b1v[3072 + hbase + aj];
    for (int t = 0; t < 512; ++t) {
      const u16* rh0 = (t == 0) ? hinit + 65536 : Xp + (size_t)(t - 1) * 131072;
      const u16* rh1 = (t == 0) ? hinit + 32768 : Xp + (size_t)(t - 1) * 131072 + 32768;
      u16* wh1 = Xw + (size_t)t * 131072 + 32768;
      if (w == 2) { pollAB(fqA, (u32)(t + 1), fqB, (u32)t); if (l == 0) tok[24] = (u32)(t + 1); }
      else { while (tok[24] < (u32)(t + 1)) __builtin_amdgcn_s_sleep(1); }
      __builtin_amdgcn_sched_barrier(0);
      asm volatile("" ::: "memory");

      const u16* a0b = rh0 + (mt * 16 + (l & 15)) * 1024 + ((l >> 4) * 8);
      const u16* a1b = rh1 + (mt * 16 + (l & 15)) * 1024 + ((l >> 4) * 8);
      f32x4 s0 = {0,0,0,0}, s1 = {0,0,0,0}, s2 = {0,0,0,0}, s3 = {0,0,0,0};
#pragma unroll
      for (int kk = 0; kk < 16; ++kk) {
        short8 e0 = *(const short8*)(a0b + (2*kk) * 32);
        short8 e1 = *(const short8*)(a0b + (2*kk+1) * 32);
        short8 f0 = *(const short8*)(a1b + (2*kk) * 32);
        short8 f1 = *(const short8*)(a1b + (2*kk+1) * 32);
        s0 = MFMA_BF16(e0, *(const short8*)(wlds + 16384 + (2*kk) * 512 + l * 8), s0);
        s1 = MFMA_BF16(e1, *(const short8*)(wlds + 16384 + (2*kk+1) * 512 + l * 8), s1);
        s2 = MFMA_BF16(f0, *(const short8*)(wlds + 32768 + (2*kk) * 512 + l * 8), s2);
        s3 = MFMA_BF16(f1, *(const short8*)(wlds + 32768 + (2*kk+1) * 512 + l * 8), s3);
      }
#pragma unroll
      for (int r = 0; r < 4; ++r)
        part1[(mt * 16 + (l >> 4) * 4 + r) * 16 + (l & 15)] = s0[r] + s1[r] + s2[r] + s3[r];

      // act1 — same-wave LDS producer/consumer
      float gi = part1[ab * 16 + aj]      + b1i;
      float gf = part1[ab * 16 + 4 + aj]  + b1fv;
      float gg = part1[ab * 16 + 8 + aj]  + b1g;
      float go = part1[ab * 16 + 12 + aj] + b1o;
      c1 = sigm(gf) * c1 + sigm(gi) * tanhf(gg);
      float h = sigm(go) * tanhf(c1);
      u32 hv = (u32)f2bf(h);
      u32 p1 = (u32)__shfl_xor((int)hv, 1);
      u32 lo = (aj & 1) ? ((p1 & 0xffff) | (hv << 16)) : ((hv & 0xffff) | (p1 << 16));
      u32 p2 = (u32)__shfl_xor((int)lo, 2);
      if (aj == 0)
        sysstore64(wh1 + ab * 1024 + hbase, (u64)lo | ((u64)p2 << 32));
      if (t == 511) h1f[ab * 1024 + hbase + aj] = h;   // normal store; kernel-end release

      asm volatile("s_waitcnt vmcnt(0)" ::: "memory");
      if (w == 3) { if (l == 0) tok[16] = (u32)(t + 1); }
      else {
        while (tok[16] < (u32)(t + 1)) __builtin_amdgcn_s_sleep(1);
        if (l == 0)
          __hip_atomic_store(&flagsB[blk], (u32)(t + 1), __ATOMIC_RELAXED,
                             __HIP_MEMORY_SCOPE_SYSTEM);
      }
    }
  }
}

// ---------------- final FC: fcw read exactly once; h1 staged in LDS ----------------
__global__ void __launch_bounds__(512) fc_kernel(const float* __restrict__ h1f,
                                                 const float* __restrict__ fcw,
                                                 const float* __restrict__ fcb,
                                                 float* __restrict__ out) {
  extern __shared__ float hls[];                  // [32][1024] fp32 = 128KB
  for (int s = threadIdx.x; s < 8192; s += 512)
    ((float4*)hls)[s] = ((const float4*)h1f)[s];
  __syncthreads();
  const int w = threadIdx.x >> 6, l = threadIdx.x & 63;
  const int vbase = blockIdx.x * 128 + w * 16;    // grid 250 x 8 waves x 16 v = 32000
  for (int vi = 0; vi < 16; ++vi) {
    const int v = vbase + vi;
    const float4* wr = (const float4*)(fcw + (size_t)v * 1024);
    float4 f0 = wr[l], f1 = wr[64 + l], f2 = wr[128 + l], f3 = wr[192 + l];
    float bias = fcb[v];
    for (int b = 0; b < 32; ++b) {
      const float4* hb = (const float4*)(hls + b * 1024);
      float4 h0 = hb[l], h1 = hb[64 + l], h2 = hb[128 + l], h3 = hb[192 + l];
      float s = f0.x*h0.x + f0.y*h0.y + f0.z*h0.z + f0.w*h0.w
              + f1.x*h1.x + f1.y*h1.y + f1.z*h1.z + f1.w*h1.w
              + f2.x*h2.x + f2.y*h2.y + f2.z*h2.z + f2.w*h2.w
              + f3.x*h3.x + f3.y*h3.y + f3.z*h3.z + f3.w*h3.w;
      s += __shfl_xor(s, 1);  s += __shfl_xor(s, 2);  s += __shfl_xor(s, 4);
      s += __shfl_xor(s, 8);  s += __shfl_xor(s, 16); s += __shfl_xor(s, 32);
      if (l == 0) out[(size_t)b * 32000 + v] = s + bias;
    }
  }
}

// ---------------- host launch ----------------
extern "C" void kernel_launch(void* const* d_in, const int* in_sizes, int n_in,
                              void* d_out, int out_size, void* d_ws, size_t ws_size,
                              hipStream_t stream) {
  const int*   x   = (const int*)d_in[0];
  const float* emb = (const float*)d_in[1];
  const float* Wi0 = (const float*)d_in[2];
  const float* bi0 = (const float*)d_in[3];
  const float* Wh0 = (const float*)d_in[4];
  const float* bh0 = (const float*)d_in[5];
  const float* Wi1 = (const float*)d_in[6];
  const float* bi1 = (const float*)d_in[7];
  const float* Wh1 = (const float*)d_in[8];
  const float* bh1 = (const float*)d_in[9];
  const float* fcw = (const float*)d_in[10];
  const float* fcb = (const float*)d_in[11];
  float* out = (float*)d_out;
  char* ws = (char*)d_ws;

  if (ws_size < WS_NEED) return;

  u16*   wbf = (u16*)(ws + OFF_W);
  float* b0v = (float*)(ws + OFF_B0);
  float* b1v = (float*)(ws + OFF_B1);
  u16*   hin = (u16*)(ws + OFF_H0);
  float* h1f = (float*)(ws + OFF_H1F);
  u16*   xe  = (u16*)(ws + OFF_XE);
  u16*   Xp  = (u16*)(ws + OFF_X0);
  u32*   flg = (u32*)(ws + OFF_FLG);

  // zero init slots + h1f every call (replays must be identical)
  hipMemsetAsync(ws + OFF_H0, 0, OFF_XE - OFF_H0, stream);

  prep_w_kernel<<<16384, 256, 0, stream>>>(Wi0, Wh0, Wi1, Wh1, wbf);
  prep_b_kernel<<<16, 256, 0, stream>>>(bi0, bh0, bi1, bh1, b0v, b1v);
  embed_kernel<<<16384, 256, 0, stream>>>(x, emb, xe);
  x0_gemm_kernel<<<dim3(32, 128), 256, 0, stream>>>(xe, wbf, b0v, Xp);

  // xe tail is dead now -> dense barrier flags A+B (zeroed per call)
  hipMemsetAsync(ws + OFF_FLG, 0, 4096, stream);

  hipFuncSetAttribute((const void*)lstm_kernel,
                      hipFuncAttributeMaxDynamicSharedMemorySize, 104576);
  lstm_kernel<<<256, 256, 104576, stream>>>(wbf, b1v, Xp, hin, h1f, flg);

  hipFuncSetAttribute((const void*)fc_kernel,
                      hipFuncAttributeMaxDynamicSharedMemorySize, 131072);
  fc_kernel<<<250, 512, 131072, stream>>>(h1f, fcw, fcb, out);
}

// Round 11
// 3415.387 us; speedup vs baseline: 2.1357x; 2.1357x over previous
//
#include <hip/hip_runtime.h>
#include <hip/hip_bf16.h>

typedef __attribute__((ext_vector_type(8))) short short8;
typedef __attribute__((ext_vector_type(4))) float f32x4;
typedef __attribute__((ext_vector_type(4))) int i32x4;
typedef unsigned short u16;
typedef unsigned int u32;
typedef unsigned long long u64;

#define MFMA_BF16(a, b, c) __builtin_amdgcn_mfma_f32_16x16x32_bf16((a), (b), (c), 0, 0, 0)

// ---------------- workspace layout (bytes) ----------------
static constexpr size_t OFF_W   = 0;                       // 4 x [4096][1024] bf16 = 32MB
static constexpr size_t OFF_B0  = 33554432;                // 4096 f32 (bi0+bh0)
static constexpr size_t OFF_B1  = OFF_B0 + 16384;          // 4096 f32 (bi1+bh1)
static constexpr size_t OFF_H0  = OFF_B1 + 16384;          // 2 init h-slots (2 x 128KB, zeroed)
static constexpr size_t OFF_H1F = OFF_H0 + 262144;         // [32][1024] f32 (final h1)
static constexpr size_t OFF_XE  = OFF_H1F + 131072;        // [16384][1024] bf16 = 32MB
static constexpr size_t OFF_X0  = OFF_XE + 33554432;       // packed gates Xp = 128MB (also slot arena)
static constexpr size_t WS_NEED = OFF_X0 + 134217728;      // ~192.5 MB
// dense barrier flags: 256 x u32 (1KB), overlaid on xe tail (dead after x0_gemm)
static constexpr size_t OFF_FLG = OFF_X0 - 4096;

// Packed gate layout: Xp[t][blk][b][j][g] (u16), addr = t*131072 + blk*512 + b*16 + j*4 + g.
// Activation thread (b=ab, j=aj) of block blk reads ONE 8B chunk = gates g=0..3.
// h slot scheme (R7/R8, proven): slot(i) = {h0[t=i], h1[t=i-1]}, written at iter i via
// SYSTEM-bypass stores (MALL only, no L2 dirtying), read at iter i+1 via NORMAL cached
// loads (XCD-L2 amplifies). slot(-1)=hinit, slot(0)=hinit+64K u16,
// slot(i>=1) = Xp + (i-1)*131072 (the gate slice bypass-consumed at iter i-1).
// Every slot address is L2-allocated at most ONCE -> cached reads never stale.

// ---------------- helpers ----------------
__device__ __forceinline__ u16 f2bf(float f) {
  u32 x = __builtin_bit_cast(u32, f);
  x += 0x7fffu + ((x >> 16) & 1u);   // RNE (inputs are finite)
  return (u16)(x >> 16);
}
__device__ __forceinline__ float bf2f(u16 u) {
  return __builtin_bit_cast(float, (u32)u << 16);
}
__device__ __forceinline__ float sigm(float x) { return 1.f / (1.f + expf(-x)); }

// system-scope (MALL-coherent) relaxed ops
__device__ __forceinline__ void sysstore64(void* p, u64 v) {
  __hip_atomic_store((u64*)p, v, __ATOMIC_RELAXED, __HIP_MEMORY_SCOPE_SYSTEM);
}
__device__ __forceinline__ u64 sysload64(const void* p) {
  return __hip_atomic_load((const u64*)p, __ATOMIC_RELAXED, __HIP_MEMORY_SCOPE_SYSTEM);
}

__device__ __forceinline__ void gload_lds16(const u16* gsrc, u16* ldst) {
  __builtin_amdgcn_global_load_lds(
      (__attribute__((address_space(1))) void*)(u16*)gsrc,
      (__attribute__((address_space(3))) void*)ldst, 16, 0, 0);
}

// ---------------- prep: fp32 weights -> bf16 ----------------
__global__ void prep_w_kernel(const float* __restrict__ Wi0, const float* __restrict__ Wh0,
                              const float* __restrict__ Wi1, const float* __restrict__ Wh1,
                              u16* __restrict__ dst) {
  size_t e = ((size_t)blockIdx.x * 256 + threadIdx.x) * 4;   // 16M elements total
  int mat = (int)(e >> 22);
  size_t off = e & ((1ull << 22) - 1);
  const float* src = (mat == 0) ? Wi0 : (mat == 1) ? Wh0 : (mat == 2) ? Wi1 : Wh1;
  float4 v = *(const float4*)(src + off);
  ushort4 o;
  o.x = f2bf(v.x); o.y = f2bf(v.y); o.z = f2bf(v.z); o.w = f2bf(v.w);
  *(ushort4*)(dst + e) = o;
}

__global__ void prep_b_kernel(const float* __restrict__ bi0, const float* __restrict__ bh0,
                              const float* __restrict__ bi1, const float* __restrict__ bh1,
                              float* __restrict__ b0, float* __restrict__ b1) {
  int i = blockIdx.x * 256 + threadIdx.x;   // 4096
  b0[i] = bi0[i] + bh0[i];
  b1[i] = bi1[i] + bh1[i];
}

// ---------------- embedding gather ----------------
__global__ void embed_kernel(const int* __restrict__ x, const float* __restrict__ emb,
                             u16* __restrict__ xe) {
  int m = blockIdx.x;            // m = t*32 + b
  int b = m & 31, t = m >> 5;
  int id = x[b * 512 + t];
  float4 v = ((const float4*)(emb + (size_t)id * 1024))[threadIdx.x];
  ushort4 o;
  o.x = f2bf(v.x); o.y = f2bf(v.y); o.z = f2bf(v.z); o.w = f2bf(v.w);
  *(ushort4*)(xe + (size_t)m * 1024 + threadIdx.x * 4) = o;
}

// ---------------- X0 GEMM -> block-packed gate layout Xp (+bias) ----------------
__global__ void x0_gemm_kernel(const u16* __restrict__ A, const u16* __restrict__ W,
                               const float* __restrict__ bias, u16* __restrict__ Xp) {
  __shared__ u16 lds[2][2][8192];   // [buf][A/B][128 rows x 64 cols]
  const int tid = threadIdx.x, l = tid & 63, w = tid >> 6;
  const int n0 = blockIdx.x * 128, m0 = blockIdx.y * 128;
  const int wm = w >> 1, wn = w & 1;
  const int row8 = l >> 3, u = l & 7;

  f32x4 acc[4][4];
#pragma unroll
  for (int a1 = 0; a1 < 4; ++a1)
#pragma unroll
    for (int a2 = 0; a2 < 4; ++a2) acc[a1][a2] = (f32x4){0.f, 0.f, 0.f, 0.f};

  auto stage = [&](int buf, int kt) {
    const int k0 = kt * 64;
#pragma unroll
    for (int q = 0; q < 4; ++q) {
      const int ld = w * 4 + q;
      const int row = ld * 8 + row8;
      const int sw = (u ^ (row & 7)) * 8;
      gload_lds16(A + (size_t)(m0 + row) * 1024 + k0 + sw, &lds[buf][0][ld * 512]);
      gload_lds16(W + (size_t)(n0 + row) * 1024 + k0 + sw, &lds[buf][1][ld * 512]);
    }
  };

  stage(0, 0);
  __syncthreads();

  for (int kt = 0; kt < 16; ++kt) {
    const int buf = kt & 1;
    if (kt < 15) stage(buf ^ 1, kt + 1);
    const u16* la = lds[buf][0];
    const u16* lb = lds[buf][1];
#pragma unroll
    for (int kk = 0; kk < 2; ++kk) {
      const int c = kk * 4 + (l >> 4);
      const int csw = (c ^ (l & 7)) * 8;    // row&7 == l&7 for all frag rows
      short8 af[4], bf[4];
#pragma unroll
      for (int mi = 0; mi < 4; ++mi) {
        int row = wm * 64 + mi * 16 + (l & 15);
        af[mi] = *(const short8*)(la + row * 64 + csw);
      }
#pragma unroll
      for (int ni = 0; ni < 4; ++ni) {
        int row = wn * 64 + ni * 16 + (l & 15);
        bf[ni] = *(const short8*)(lb + row * 64 + csw);
      }
#pragma unroll
      for (int mi = 0; mi < 4; ++mi)
#pragma unroll
        for (int ni = 0; ni < 4; ++ni)
          acc[mi][ni] = MFMA_BF16(af[mi], bf[ni], acc[mi][ni]);
    }
    __syncthreads();
  }

  // epilogue: packed write Xp[t][blkid][b][j][g]
#pragma unroll
  for (int ni = 0; ni < 4; ++ni) {
    int col = n0 + wn * 64 + ni * 16 + (l & 15);
    int g = col >> 10, blkid = (col & 1023) >> 2, j = col & 3;
    float bv = bias[col];
#pragma unroll
    for (int mi = 0; mi < 4; ++mi) {
#pragma unroll
      for (int r = 0; r < 4; ++r) {
        int row = m0 + wm * 64 + mi * 16 + (l >> 4) * 4 + r;
        int t = row >> 5, b = row & 31;
        Xp[(size_t)t * 131072 + blkid * 512 + b * 16 + j * 4 + g] =
            f2bf(acc[mi][ni][r] + bv);
      }
    }
  }
}

// ---------------- persistent recurrent kernel (R8 structure, proven) ----------------
// 256 blocks (1/CU), 256 threads (4 waves). Iter i = layer0(t=i) + layer1(t=i-1).
// Dense-flag barrier: writers post 4B system store; wave 0 polls all 256 flags with
// ONE 16B bypass load per lane (4 flags/lane). Gate chunk prefetched under the poll.
__launch_bounds__(256, 1)
__global__ void lstm_kernel(const u16* __restrict__ wbf, const float* __restrict__ b1v,
                            const u16* __restrict__ Xp, u16* __restrict__ hinit,
                            float* __restrict__ h1f, u32* __restrict__ flagsD) {
  extern __shared__ char smem[];
  u16* wlds = (u16*)smem;                          // 3 * 16384 u16 = 98304 B
  float* gates0 = (float*)(smem + 98304);          // [32][16]  Wh0.h0
  float* part1  = (float*)(smem + 98304 + 2048);   // [32][16]  Wi1.h0
  float* wh1p   = (float*)(smem + 98304 + 4096);   // [32][16]  Wh1.h1

  const int tid = threadIdx.x;
  const int l = tid & 63, w = tid >> 6;
  const int blk = blockIdx.x;
  const int hbase = blk * 4;
  u16* Xw = (u16*)Xp;                              // slot writes into consumed gate slices

  // ---- fill weight LDS in MFMA fragment order
  for (int m = 0; m < 3; ++m) {
    const u16* Wm = wbf + (size_t)(m + 1) * (4096 * 1024);   // 1=Wh0, 2=Wi1, 3=Wh1
    for (int s = tid; s < 2048; s += 256) {
      int kk = s >> 6, ll = s & 63;
      int nl = ll & 15, hi = ll >> 4;
      int gr = (nl >> 2) * 1024 + hbase + (nl & 3);
      short8 v = *(const short8*)(Wm + (size_t)gr * 1024 + kk * 32 + hi * 8);
      *(short8*)(wlds + m * 16384 + kk * 512 + ll * 8) = v;
    }
  }
  __syncthreads();

  float cst = 0.f;                                 // threads 0..127: c0; 128..255: c1
  const int at = tid & 127, ab = at >> 2, aj = at & 3;
  const int mt = w & 1;

  float b1i = 0.f, b1fv = 0.f, b1g = 0.f, b1o = 0.f;
  if (tid >= 128) {
    b1i  = b1v[hbase + aj];
    b1fv = b1v[1024 + hbase + aj];
    b1g  = b1v[2048 + hbase + aj];
    b1o  = b1v[3072 + hbase + aj];
  }

  // gate chunk for step 0 (8B bypass; holds gates g=0..3 for this thread's (ab,aj))
  u64 gchunk = 0;
  if (tid < 128)
    gchunk = sysload64(Xp + blk * 512 + ab * 16 + aj * 4);

  const u32* fquad = flagsD + l * 4;               // wave-0 poll: 4 flags per lane

  for (int i = 0; i <= 512; ++i) {
    const u16* slot_r = (i == 0) ? hinit
                      : (i == 1) ? hinit + 65536
                                 : Xp + (size_t)(i - 2) * 131072;
    u16* slot_w = (i == 0) ? hinit + 65536
                           : Xw + (size_t)(i - 1) * 131072;

    asm volatile("" ::: "memory");   // pin loads below the previous barrier

    // ---- preload ALL h fragments: 32 x 16B NORMAL cached loads (L2-amplified broadcast)
    const u16* abase = slot_r + (w < 2 ? 0 : 32768)
                     + (mt * 16 + (l & 15)) * 1024 + ((l >> 4) * 8);
    short8 ar[32];
#pragma unroll
    for (int kk = 0; kk < 32; ++kk)
      ar[kk] = *(const short8*)(abase + kk * 32);

    if (w < 2) {   // waves 0,1: Wh0.h0 and Wi1.h0 (two independent chains each)
      f32x4 a0a = {0,0,0,0}, a0b = {0,0,0,0}, a1a = {0,0,0,0}, a1b = {0,0,0,0};
#pragma unroll
      for (int kk = 0; kk < 16; ++kk) {
        a0a = MFMA_BF16(ar[2 * kk],     *(const short8*)(wlds + (2 * kk) * 512 + l * 8), a0a);
        a1a = MFMA_BF16(ar[2 * kk],     *(const short8*)(wlds + 16384 + (2 * kk) * 512 + l * 8), a1a);
        a0b = MFMA_BF16(ar[2 * kk + 1], *(const short8*)(wlds + (2 * kk + 1) * 512 + l * 8), a0b);
        a1b = MFMA_BF16(ar[2 * kk + 1], *(const short8*)(wlds + 16384 + (2 * kk + 1) * 512 + l * 8), a1b);
      }
#pragma unroll
      for (int r = 0; r < 4; ++r) {
        int row = mt * 16 + (l >> 4) * 4 + r, col = l & 15;
        gates0[row * 16 + col] = a0a[r] + a0b[r];
        part1[row * 16 + col]  = a1a[r] + a1b[r];
      }
    } else {       // waves 2,3: Wh1.h1
      f32x4 a0a = {0,0,0,0}, a0b = {0,0,0,0};
#pragma unroll
      for (int kk = 0; kk < 16; ++kk) {
        a0a = MFMA_BF16(ar[2 * kk],     *(const short8*)(wlds + 2 * 16384 + (2 * kk) * 512 + l * 8), a0a);
        a0b = MFMA_BF16(ar[2 * kk + 1], *(const short8*)(wlds + 2 * 16384 + (2 * kk + 1) * 512 + l * 8), a0b);
      }
#pragma unroll
      for (int r = 0; r < 4; ++r) {
        int row = mt * 16 + (l >> 4) * 4 + r, col = l & 15;
        wh1p[row * 16 + col] = a0a[r] + a0b[r];
      }
    }
    __syncthreads();

    // ---- activations + h slot store (packed 8B system store per 4 dims)
    if (tid < 128) {
      if (i < 512) {
        float gi = gates0[ab * 16 + aj]      + bf2f((u16)(gchunk));
        float gf = gates0[ab * 16 + 4 + aj]  + bf2f((u16)(gchunk >> 16));
        float gg = gates0[ab * 16 + 8 + aj]  + bf2f((u16)(gchunk >> 32));
        float go = gates0[ab * 16 + 12 + aj] + bf2f((u16)(gchunk >> 48));
        cst = sigm(gf) * cst + sigm(gi) * tanhf(gg);
        float h = sigm(go) * tanhf(cst);
        u32 hv = (u32)f2bf(h);
        u32 p1 = (u32)__shfl_xor((int)hv, 1);
        u32 lo = (aj & 1) ? ((p1 & 0xffff) | (hv << 16)) : ((hv & 0xffff) | (p1 << 16));
        u32 p2 = (u32)__shfl_xor((int)lo, 2);
        if (aj == 0)
          sysstore64(slot_w + ab * 1024 + hbase, (u64)lo | ((u64)p2 << 32));
      }
    } else {
      if (i >= 1) {
        float gi = part1[ab * 16 + aj]      + wh1p[ab * 16 + aj]      + b1i;
        float gf = part1[ab * 16 + 4 + aj]  + wh1p[ab * 16 + 4 + aj]  + b1fv;
        float gg = part1[ab * 16 + 8 + aj]  + wh1p[ab * 16 + 8 + aj]  + b1g;
        float go = part1[ab * 16 + 12 + aj] + wh1p[ab * 16 + 12 + aj] + b1o;
        cst = sigm(gf) * cst + sigm(gi) * tanhf(gg);
        float h = sigm(go) * tanhf(cst);
        u32 hv = (u32)f2bf(h);
        u32 p1 = (u32)__shfl_xor((int)hv, 1);
        u32 lo = (aj & 1) ? ((p1 & 0xffff) | (hv << 16)) : ((hv & 0xffff) | (p1 << 16));
        u32 p2 = (u32)__shfl_xor((int)lo, 2);
        if (aj == 0)
          sysstore64(slot_w + 32768 + ab * 1024 + hbase, (u64)lo | ((u64)p2 << 32));
        if (i == 512) h1f[ab * 1024 + hbase + aj] = h;
      }
    }

    if (i == 512) break;                 // done; no final barrier needed

    // ---- dense-flag barrier: post, prefetch gates, wave-0 poll
    __syncthreads();                     // all h system-stores drained (vmcnt 0, all waves)
    const u32 target = (u32)(i + 1);
    if (tid == 0)
      __hip_atomic_store(&flagsD[blk], target, __ATOMIC_RELAXED, __HIP_MEMORY_SCOPE_SYSTEM);

    // prefetch next step's gate chunk under the barrier wait
    if (tid < 128 && i + 1 < 512)
      gchunk = sysload64(Xp + (size_t)(i + 1) * 131072 + blk * 512 + ab * 16 + aj * 4);

    if (w == 0) {                        // 64 lanes x 4 flags = all 256, one 16B load/lane
      while (true) {
        i32x4 v;
        asm volatile("global_load_dwordx4 %0, %1, off sc0 sc1"
                     : "=&v"(v) : "v"(fquad));
        asm volatile("s_waitcnt vmcnt(0)" ::: "memory");
        u32 m01 = min((u32)v.x, (u32)v.y);
        u32 m23 = min((u32)v.z, (u32)v.w);
        if (__all(min(m01, m23) >= target)) break;
      }
    }
    __syncthreads();                     // whole block proceeds once wave 0 confirms
  }
}

// ---------------- final FC: fcw read exactly once; h1 staged in LDS ----------------
__global__ void __launch_bounds__(512) fc_kernel(const float* __restrict__ h1f,
                                                 const float* __restrict__ fcw,
                                                 const float* __restrict__ fcb,
                                                 float* __restrict__ out) {
  extern __shared__ float hls[];                  // [32][1024] fp32 = 128KB
  for (int s = threadIdx.x; s < 8192; s += 512)
    ((float4*)hls)[s] = ((const float4*)h1f)[s];
  __syncthreads();
  const int w = threadIdx.x >> 6, l = threadIdx.x & 63;
  const int vbase = blockIdx.x * 128 + w * 16;    // grid 250 x 8 waves x 16 v = 32000
  for (int vi = 0; vi < 16; ++vi) {
    const int v = vbase + vi;
    const float4* wr = (const float4*)(fcw + (size_t)v * 1024);
    float4 f0 = wr[l], f1 = wr[64 + l], f2 = wr[128 + l], f3 = wr[192 + l];
    float bias = fcb[v];
    for (int b = 0; b < 32; ++b) {
      const float4* hb = (const float4*)(hls + b * 1024);
      float4 h0 = hb[l], h1 = hb[64 + l], h2 = hb[128 + l], h3 = hb[192 + l];
      float s = f0.x*h0.x + f0.y*h0.y + f0.z*h0.z + f0.w*h0.w
              + f1.x*h1.x + f1.y*h1.y + f1.z*h1.z + f1.w*h1.w
              + f2.x*h2.x + f2.y*h2.y + f2.z*h2.z + f2.w*h2.w
              + f3.x*h3.x + f3.y*h3.y + f3.z*h3.z + f3.w*h3.w;
      s += __shfl_xor(s, 1);  s += __shfl_xor(s, 2);  s += __shfl_xor(s, 4);
      s += __shfl_xor(s, 8);  s += __shfl_xor(s, 16); s += __shfl_xor(s, 32);
      if (l == 0) out[(size_t)b * 32000 + v] = s + bias;
    }
  }
}

// ---------------- host launch ----------------
extern "C" void kernel_launch(void* const* d_in, const int* in_sizes, int n_in,
                              void* d_out, int out_size, void* d_ws, size_t ws_size,
                              hipStream_t stream) {
  const int*   x   = (const int*)d_in[0];
  const float* emb = (const float*)d_in[1];
  const float* Wi0 = (const float*)d_in[2];
  const float* bi0 = (const float*)d_in[3];
  const float* Wh0 = (const float*)d_in[4];
  const float* bh0 = (const float*)d_in[5];
  const float* Wi1 = (const float*)d_in[6];
  const float* bi1 = (const float*)d_in[7];
  const float* Wh1 = (const float*)d_in[8];
  const float* bh1 = (const float*)d_in[9];
  const float* fcw = (const float*)d_in[10];
  const float* fcb = (const float*)d_in[11];
  float* out = (float*)d_out;
  char* ws = (char*)d_ws;

  if (ws_size < WS_NEED) return;

  u16*   wbf = (u16*)(ws + OFF_W);
  float* b0v = (float*)(ws + OFF_B0);
  float* b1v = (float*)(ws + OFF_B1);
  u16*   hin = (u16*)(ws + OFF_H0);
  float* h1f = (float*)(ws + OFF_H1F);
  u16*   xe  = (u16*)(ws + OFF_XE);
  u16*   Xp  = (u16*)(ws + OFF_X0);
  u32*   flg = (u32*)(ws + OFF_FLG);

  // zero init slots + h1f every call (replays must be identical)
  hipMemsetAsync(ws + OFF_H0, 0, OFF_XE - OFF_H0, stream);

  prep_w_kernel<<<16384, 256, 0, stream>>>(Wi0, Wh0, Wi1, Wh1, wbf);
  prep_b_kernel<<<16, 256, 0, stream>>>(bi0, bh0, bi1, bh1, b0v, b1v);
  embed_kernel<<<16384, 256, 0, stream>>>(x, emb, xe);
  x0_gemm_kernel<<<dim3(32, 128), 256, 0, stream>>>(xe, wbf, b0v, Xp);

  // xe tail is dead now -> dense barrier flags (zeroed per call)
  hipMemsetAsync(ws + OFF_FLG, 0, 4096, stream);

  hipFuncSetAttribute((const void*)lstm_kernel,
                      hipFuncAttributeMaxDynamicSharedMemorySize, 104448);
  lstm_kernel<<<256, 256, 104448, stream>>>(wbf, b1v, Xp, hin, h1f, flg);

  hipFuncSetAttribute((const void*)fc_kernel,
                      hipFuncAttributeMaxDynamicSharedMemorySize, 131072);
  fc_kernel<<<250, 512, 131072, stream>>>(h1f, fcw, fcb, out);
}